// Round 17
// baseline (197.856 us; speedup 1.0000x reference)
//
#include <hip/hip_runtime.h>
#include <hip/hip_bf16.h>
#include <stdint.h>

#define DIM 2048
#define NH 16
#define NKV 4
#define HD 128
#define BATCH 2
#define SEQ 2048

typedef unsigned short ushort_t;
typedef __attribute__((ext_vector_type(8))) short short8;
typedef __attribute__((ext_vector_type(4))) float f32x4;
typedef __attribute__((ext_vector_type(16))) float f32x16;

__device__ inline ushort_t f2b(float f) {
    union { float f; uint32_t u; } v; v.f = f;
    uint32_t r = (v.u + 0x7fffu + ((v.u >> 16) & 1u)) >> 16;
    return (ushort_t)r;
}

// native 2^x (v_exp_f32); libm exp2f goes through OCML precise path (r10: −13us on attn)
__device__ inline float fexp2(float x) {
#if __has_builtin(__builtin_amdgcn_exp2f)
    return __builtin_amdgcn_exp2f(x);
#else
    float r; asm("v_exp_f32 %0, %1" : "=v"(r) : "v"(x)); return r;
#endif
}

// packed f32x2 -> bf16x2 (T12 recipe; register-only asm, schedulable)
__device__ inline uint32_t pk2bf(float a, float b) {
    uint32_t r;
    asm("v_cvt_pk_bf16_f32 %0, %1, %2" : "=v"(r) : "v"(a), "v"(b));
    return r;
}

// merged cast: x->xb, wq/wk/wv->wqkvb (fused), wproj->wprojb  (one launch)
__global__ void cast_all(const float* __restrict__ x, const float* __restrict__ wq,
                         const float* __restrict__ wk, const float* __restrict__ wv,
                         const float* __restrict__ wp,
                         ushort_t* __restrict__ xb, ushort_t* __restrict__ wqkvb,
                         ushort_t* __restrict__ wprojb) {
    const int stride = gridDim.x * blockDim.x;
    for (int i = blockIdx.x * blockDim.x + threadIdx.x; i < 4718592; i += stride) {
        const float* s; ushort_t* d; int off;
        if (i < 2097152)      { s = x;  d = xb;               off = i; }
        else if (i < 3145728) { s = wq; d = wqkvb;            off = i - 2097152; }
        else if (i < 3407872) { s = wk; d = wqkvb + 4194304;  off = i - 3145728; }
        else if (i < 3670016) { s = wv; d = wqkvb + 5242880;  off = i - 3407872; }
        else                  { s = wp; d = wprojb;           off = i - 3670016; }
        float4 v = ((const float4*)s)[off];
        ushort4 o;
        o.x = f2b(v.x); o.y = f2b(v.y); o.z = f2b(v.z); o.w = f2b(v.w);
        ((ushort4*)d)[off] = o;
    }
}

__device__ inline void gload_lds16(const ushort_t* g, ushort_t* l) {
    __builtin_amdgcn_global_load_lds((const __attribute__((address_space(1))) void*)g,
                                     (__attribute__((address_space(3))) void*)l, 16, 0, 0);
}

// C[m][n] = sum_k A[m][k]*B[n][k], fp32 C (proj GEMM). BK=64 + source-XOR swizzle.
// T1 XCD-swizzled grid.
__launch_bounds__(256, 2)
__global__ void gemm_bt(const ushort_t* __restrict__ A, const ushort_t* __restrict__ Bm,
                        float* __restrict__ C, int M, int N, int K) {
    __shared__ ushort_t lA[128 * 64];
    __shared__ ushort_t lB[128 * 64];
    const int t = threadIdx.x;
    const int lane = t & 63;
    const int w = t >> 6;
    const int wr = w >> 1, wc = w & 1;
    const int g = lane >> 4, l16 = lane & 15;
    const int nwg = gridDim.x * gridDim.y;
    const int bid = blockIdx.y * gridDim.x + blockIdx.x;
    const int cpx = nwg >> 3;
    const int swz = (bid & 7) * cpx + (bid >> 3);
    const int nbx = gridDim.x;
    const int m0 = (swz / nbx) * 128, n0 = (swz % nbx) * 128;

    f32x4 acc[4][4];
#pragma unroll
    for (int i = 0; i < 4; i++)
#pragma unroll
        for (int j = 0; j < 4; j++) acc[i][j] = (f32x4){0, 0, 0, 0};

    const int row_s = t >> 3;              // 0..31 (+ i*32)
    const int cx = t & 7;                  // chunk 0..7; source chunk = cx ^ (row&7)
    const int xr = (lane & 7);             // read-side XOR term

    for (int kt = 0; kt < (K >> 6); ++kt) {
        const int k0 = kt * 64;
        __syncthreads();
#pragma unroll
        for (int i = 0; i < 4; i++) {
            const int ra = i * 32 + row_s;
            gload_lds16(A + (size_t)(m0 + ra) * K + k0 + ((cx ^ (row_s & 7)) * 8), lA + i * 2048 + t * 8);
            gload_lds16(Bm + (size_t)(n0 + ra) * K + k0 + ((cx ^ (row_s & 7)) * 8), lB + i * 2048 + t * 8);
        }
        __syncthreads();
#pragma unroll
        for (int kk = 0; kk < 2; kk++) {
            short8 af[4], bf[4];
#pragma unroll
            for (int i = 0; i < 4; i++) {
                af[i] = *(const short8*)(lA + (wr * 64 + i * 16 + l16) * 64 + (((kk * 4 + g) ^ xr) * 8));
                bf[i] = *(const short8*)(lB + (wc * 64 + i * 16 + l16) * 64 + (((kk * 4 + g) ^ xr) * 8));
            }
#pragma unroll
            for (int i = 0; i < 4; i++)
#pragma unroll
                for (int j = 0; j < 4; j++)
                    acc[i][j] = __builtin_amdgcn_mfma_f32_16x16x32_bf16(af[i], bf[j], acc[i][j], 0, 0, 0);
        }
    }
#pragma unroll
    for (int i = 0; i < 4; i++)
#pragma unroll
        for (int j = 0; j < 4; j++) {
            int rb = m0 + wr * 64 + i * 16 + g * 4;
            int cb = n0 + wc * 64 + j * 16 + l16;
#pragma unroll
            for (int r = 0; r < 4; r++)
                C[(size_t)(rb + r) * N + cb] = acc[i][j][r];
        }
}

// QKV GEMM (BK=64 + source swizzle) with fused RMSNorm+RoPE+gain epilogue (q/k) and
// transposed V write. n-tile == one head; cm[j] remap puts both RoPE partners in-lane.
__launch_bounds__(256, 2)
__global__ void gemm_qkv(const ushort_t* __restrict__ A, const ushort_t* __restrict__ Bm,
                         const float* __restrict__ qgain,
                         ushort_t* __restrict__ qb, ushort_t* __restrict__ kb,
                         ushort_t* __restrict__ vtb) {
    const int K = 2048;
    __shared__ ushort_t lA[128 * 64];
    __shared__ ushort_t lB[128 * 64];
    __shared__ float psum[2][128];
    const int t = threadIdx.x;
    const int lane = t & 63;
    const int w = t >> 6;
    const int wr = w >> 1, wc = w & 1;
    const int g = lane >> 4, l16 = lane & 15;
    const int nwg = gridDim.x * gridDim.y;
    const int bid = blockIdx.y * gridDim.x + blockIdx.x;
    const int cpx = nwg >> 3;
    const int swz = (bid & 7) * cpx + (bid >> 3);
    const int nt = swz % 24;                 // head tile: 0..15 q, 16..19 k, 20..23 v
    const int m0 = (swz / 24) * 128, n0 = nt * 128;

    int cm[4];
    cm[0] = wc * 32 + l16;
    cm[1] = wc * 32 + 16 + l16;
    cm[2] = cm[0] + 64;
    cm[3] = cm[1] + 64;

    f32x4 acc[4][4];
#pragma unroll
    for (int i = 0; i < 4; i++)
#pragma unroll
        for (int j = 0; j < 4; j++) acc[i][j] = (f32x4){0, 0, 0, 0};

    const int row_s = t >> 3;
    const int cx = t & 7;
    const int xr = (lane & 7);

    for (int kt = 0; kt < (K >> 6); ++kt) {
        const int k0 = kt * 64;
        __syncthreads();
#pragma unroll
        for (int i = 0; i < 4; i++) {
            const int ra = i * 32 + row_s;
            gload_lds16(A + (size_t)(m0 + ra) * K + k0 + ((cx ^ (row_s & 7)) * 8), lA + i * 2048 + t * 8);
            gload_lds16(Bm + (size_t)(n0 + ra) * K + k0 + ((cx ^ (row_s & 7)) * 8), lB + i * 2048 + t * 8);
        }
        __syncthreads();
#pragma unroll
        for (int kk = 0; kk < 2; kk++) {
            short8 af[4], bf[4];
#pragma unroll
            for (int i = 0; i < 4; i++) {
                af[i] = *(const short8*)(lA + (wr * 64 + i * 16 + l16) * 64 + (((kk * 4 + g) ^ xr) * 8));
                bf[i] = *(const short8*)(lB + cm[i] * 64 + (((kk * 4 + g) ^ xr) * 8));
            }
#pragma unroll
            for (int i = 0; i < 4; i++)
#pragma unroll
                for (int j = 0; j < 4; j++)
                    acc[i][j] = __builtin_amdgcn_mfma_f32_16x16x32_bf16(af[i], bf[j], acc[i][j], 0, 0, 0);
        }
    }

    const int b = m0 >> 11;          // token block lies within one batch (2048 % 128 == 0)
    const int s0 = m0 & 2047;

    if (nt < 20) {
        float ssq[4][4];
#pragma unroll
        for (int i = 0; i < 4; i++)
#pragma unroll
            for (int r = 0; r < 4; r++) {
                float v = 0.0f;
#pragma unroll
                for (int j = 0; j < 4; j++) v += acc[i][j][r] * acc[i][j][r];
#pragma unroll
                for (int m = 1; m < 16; m <<= 1) v += __shfl_xor(v, m, 64);
                ssq[i][r] = v;
            }
        if (l16 == 0) {
#pragma unroll
            for (int i = 0; i < 4; i++)
#pragma unroll
                for (int r = 0; r < 4; r++)
                    psum[wc][wr * 64 + i * 16 + g * 4 + r] = ssq[i][r];
        }
        __syncthreads();

        const float gsc = (nt < 16) ? qgain[nt] * (0.08838834764831845f * 1.4426950408889634f)
                                    : 1.0f;
        ushort_t* outp = (nt < 16) ? qb + (size_t)(b * NH + nt) * SEQ * HD
                                   : kb + (size_t)(b * NKV + (nt - 16)) * SEQ * HD;
        const float inv0 = exp2f(-(float)cm[0] * (13.287712379549449f / 64.0f));
        const float inv1 = exp2f(-(float)cm[1] * (13.287712379549449f / 64.0f));
#pragma unroll
        for (int i = 0; i < 4; i++)
#pragma unroll
            for (int r = 0; r < 4; r++) {
                const int sloc = wr * 64 + i * 16 + g * 4 + r;
                const float tot = psum[0][sloc] + psum[1][sloc];
                const float rg = rsqrtf(tot * (1.0f / 128.0f) + 1.1920929e-07f) * gsc;
                const float fs = (float)(s0 + sloc);
                ushort_t* orow = outp + (size_t)(s0 + sloc) * HD;
#pragma unroll
                for (int jp = 0; jp < 2; jp++) {
                    float x1 = acc[i][jp][r], x2 = acc[i][jp + 2][r];
                    float sn, c;
                    __sincosf(fs * (jp ? inv1 : inv0), &sn, &c);
                    orow[cm[jp]]      = f2b((x1 * c + x2 * sn) * rg);
                    orow[cm[jp] + 64] = f2b((x2 * c - x1 * sn) * rg);
                }
            }
    } else {
        ushort_t* vout = vtb + (size_t)((b * NKV + (nt - 20)) * HD) * SEQ;
#pragma unroll
        for (int i = 0; i < 4; i++)
#pragma unroll
            for (int j = 0; j < 4; j++) {
                ushort4 o;
                o.x = f2b(acc[i][j][0]); o.y = f2b(acc[i][j][1]);
                o.z = f2b(acc[i][j][2]); o.w = f2b(acc[i][j][3]);
                *(ushort4*)(vout + (size_t)cm[j] * SEQ + s0 + wr * 64 + i * 16 + g * 4) = o;
            }
    }
}

#define KVB 64

// 32x32 swapped-QK^T flash attention. 512-thread / 8-wave blocks covering 256 q-rows
// (each wave keeps the proven 32-q inner loop). Each block processes TWO 256-q tiles
// sequentially — heavy QT=7-p then light QT=p — so every block does exactly 36 kv-tiles
// (perfect balance at 1 block/CU, grid 256). Per 256 q-rows vs the r12 2-block scheme:
// staging loads and barriers halve, LDS write-ops halve; inner loop/swizzles unchanged.
// T14 single-barrier dbuf: per iter {ds_write kt+1 -> buf[kt+1&1]; global-load kt+2 ->
// regs; compute buf[kt&1]; barrier}. K LDS [64 kv][128 d]: chunk c at slot c^(row&15).
// V^T LDS [128 d][64 kv]: chunk c at slot c^(row&7).
__launch_bounds__(512, 2)
__global__ void attn(const ushort_t* __restrict__ qbuf, const ushort_t* __restrict__ kbuf,
                     const ushort_t* __restrict__ vtbuf, ushort_t* __restrict__ ybuf) {
    __shared__ ushort_t Klds[2][KVB * HD];
    __shared__ ushort_t Vlds[2][HD * KVB];

    const int idx = blockIdx.x;
    const int xcd = idx & 7;
    const int bh = xcd * 4 + ((idx >> 3) & 3);   // 4 bh per XCD -> K/V L2 resident
    const int p = idx >> 5;                      // 0..7 pair index
    const int b = bh >> 4, hh = bh & 15;
    const int kvh = hh >> 2;
    const int t = threadIdx.x;
    const int w = t >> 6, lane = t & 63;
    const int l31 = lane & 31, hf = lane >> 5;

    const ushort_t* Qp = qbuf + (size_t)(b * NH + hh) * SEQ * HD;
    const ushort_t* Kp = kbuf + (size_t)(b * NKV + kvh) * SEQ * HD;
    const ushort_t* Vtp = vtbuf + (size_t)(b * NKV + kvh) * HD * SEQ;

    // staging (512 threads): K tile = 64 rows x 16 chunks(16B); V^T tile = 128 rows x 8 chunks.
    // 2 chunks/thread each. Linear global reads; swizzle applied on ds_write.
    const int k_row = t >> 3;          // 0..63
    const int k_c0 = (t & 7) * 2;      // chunks k_c0, k_c0+1
    const int v_row = t >> 2;          // 0..127
    const int v_c0 = (t & 3) * 2;      // chunks v_c0, v_c0+1

    short8 kreg[2], vreg[2];

#pragma unroll
    for (int phase = 0; phase < 2; phase++) {
        const int QT = phase ? p : 7 - p;        // heavy first
        const int qbase = QT * 256 + w * 32;
        const int ntiles = QT * 4 + 4;

        short8 aq[8];
#pragma unroll
        for (int dc = 0; dc < 8; dc++)
            aq[dc] = *(const short8*)(Qp + (size_t)(qbase + l31) * HD + dc * 16 + hf * 8);

        f32x16 y[4];
#pragma unroll
        for (int db = 0; db < 4; db++)
#pragma unroll
            for (int r = 0; r < 16; r++) y[db][r] = 0.0f;
        float mrun = -1e30f, lrun = 0.0f;

        // prologue: tile 0 -> regs -> buf0; tile 1 -> regs; barrier
#pragma unroll
        for (int i = 0; i < 2; i++) {
            kreg[i] = *(const short8*)(Kp + (size_t)k_row * HD + (k_c0 + i) * 8);
            vreg[i] = *(const short8*)(Vtp + (size_t)v_row * SEQ + (v_c0 + i) * 8);
        }
        {
            ushort_t* kd = Klds[0] + k_row * HD;
            ushort_t* vd = Vlds[0] + v_row * KVB;
#pragma unroll
            for (int i = 0; i < 2; i++)
                *(short8*)(kd + (((k_c0 + i) ^ (k_row & 15)) * 8)) = kreg[i];
#pragma unroll
            for (int i = 0; i < 2; i++)
                *(short8*)(vd + (((v_c0 + i) ^ (v_row & 7)) * 8)) = vreg[i];
        }
        if (ntiles > 1) {
#pragma unroll
            for (int i = 0; i < 2; i++) {
                kreg[i] = *(const short8*)(Kp + (size_t)(KVB + k_row) * HD + (k_c0 + i) * 8);
                vreg[i] = *(const short8*)(Vtp + (size_t)v_row * SEQ + KVB + (v_c0 + i) * 8);
            }
        }
        __syncthreads();

        for (int kt = 0; kt < ntiles; ++kt) {
            const int kv0 = kt * KVB;
            // 1) publish tile kt+1 (from regs) into the other buffer
            if (kt + 1 < ntiles) {
                ushort_t* kd = Klds[(kt + 1) & 1] + k_row * HD;
                ushort_t* vd = Vlds[(kt + 1) & 1] + v_row * KVB;
#pragma unroll
                for (int i = 0; i < 2; i++)
                    *(short8*)(kd + (((k_c0 + i) ^ (k_row & 15)) * 8)) = kreg[i];
#pragma unroll
                for (int i = 0; i < 2; i++)
                    *(short8*)(vd + (((v_c0 + i) ^ (v_row & 7)) * 8)) = vreg[i];
            }
            // 2) issue global loads for tile kt+2 (latency hides under compute)
            if (kt + 2 < ntiles) {
                const int nkv0 = kv0 + 2 * KVB;
#pragma unroll
                for (int i = 0; i < 2; i++) {
                    kreg[i] = *(const short8*)(Kp + (size_t)(nkv0 + k_row) * HD + (k_c0 + i) * 8);
                    vreg[i] = *(const short8*)(Vtp + (size_t)v_row * SEQ + nkv0 + (v_c0 + i) * 8);
                }
            }

            // 3) compute tile kt from buf[kt&1]
            if (kv0 <= qbase + 31) {          // warp-uniform compute guard
                const ushort_t* Kl = Klds[kt & 1];
                const ushort_t* Vl = Vlds[kt & 1];

                f32x16 s0v, s1v;
#pragma unroll
                for (int r = 0; r < 16; r++) { s0v[r] = 0.0f; s1v[r] = 0.0f; }
#pragma unroll
                for (int dc = 0; dc < 8; dc++) {
                    short8 ak0 = *(const short8*)(Kl + (size_t)(l31) * HD      + (((dc * 2 + hf) ^ (l31 & 15)) * 8));
                    short8 ak1 = *(const short8*)(Kl + (size_t)(32 + l31) * HD + (((dc * 2 + hf) ^ (l31 & 15)) * 8));
                    s0v = __builtin_amdgcn_mfma_f32_32x32x16_bf16(ak0, aq[dc], s0v, 0, 0, 0);
                    s1v = __builtin_amdgcn_mfma_f32_32x32x16_bf16(ak1, aq[dc], s1v, 0, 0, 0);
                }

                // ---- causal mask ----
                const int qabs = qbase + l31;
                if (kv0 + 63 > qbase) {
#pragma unroll
                    for (int r = 0; r < 16; r++) {
                        int kvr = kv0 + (r & 3) + 8 * (r >> 2) + 4 * hf;
                        if (kvr > qabs)      s0v[r] = -1e30f;
                        if (kvr + 32 > qabs) s1v[r] = -1e30f;
                    }
                }

                // ---- softmax (per-lane q), online, exp2 domain, defer-max ----
                float mt = -1e30f;
#pragma unroll
                for (int r = 0; r < 16; r++) mt = fmaxf(mt, fmaxf(s0v[r], s1v[r]));
                mt = fmaxf(mt, __shfl_xor(mt, 32, 64));
                if (!__all(mt <= mrun + 8.0f)) {
                    float mn = fmaxf(mrun, mt);
                    float al = fexp2(mrun - mn);
                    mrun = mn;
                    lrun *= al;
#pragma unroll
                    for (int r = 0; r < 16; r++) {
                        float alr = __shfl(al, (r & 3) + 8 * (r >> 2) + 4 * hf, 64);
#pragma unroll
                        for (int db = 0; db < 4; db++) y[db][r] *= alr;
                    }
                }
                float sum = 0.0f;
#pragma unroll
                for (int r = 0; r < 16; r++) {
                    float p0 = fexp2(s0v[r] - mrun);
                    float p1 = fexp2(s1v[r] - mrun);
                    s0v[r] = p0; s1v[r] = p1;
                    sum += p0 + p1;
                }
                sum += __shfl_xor(sum, 32, 64);
                lrun += sum;

                // ---- P -> A-fragments: cvt_pk pack + lane^32 exchange ----
                union PW { short8 v; uint32_t wd[4]; } pa[4];
#pragma unroll
                for (int blk = 0; blk < 2; blk++) {
#pragma unroll
                    for (int ks2 = 0; ks2 < 2; ks2++) {
#pragma unroll
                        for (int t2 = 0; t2 < 2; t2++) {
                            float a0 = blk ? s1v[8 * ks2 + 2 * t2]         : s0v[8 * ks2 + 2 * t2];
                            float a1 = blk ? s1v[8 * ks2 + 2 * t2 + 1]     : s0v[8 * ks2 + 2 * t2 + 1];
                            float b0 = blk ? s1v[8 * ks2 + 4 + 2 * t2]     : s0v[8 * ks2 + 4 + 2 * t2];
                            float b1 = blk ? s1v[8 * ks2 + 4 + 2 * t2 + 1] : s0v[8 * ks2 + 4 + 2 * t2 + 1];
                            uint32_t pw = pk2bf(a0, a1);   // low pair
                            uint32_t qw = pk2bf(b0, b1);   // high pair
                            uint32_t send = hf ? pw : qw;
                            uint32_t recv = (uint32_t)__shfl_xor((int)send, 32, 64);
                            pa[blk * 2 + ks2].wd[t2]     = hf ? recv : pw;
                            pa[blk * 2 + ks2].wd[t2 + 2] = hf ? qw : recv;
                        }
                    }
                }

                // ---- PV: y[db] += sum_ks pa[ks] x V^T-frag ----
#pragma unroll
                for (int ks = 0; ks < 4; ks++) {
#pragma unroll
                    for (int db = 0; db < 4; db++) {
                        short8 bv = *(const short8*)(Vl + (size_t)(db * 32 + l31) * KVB
                                                     + (((ks * 2 + hf) ^ (l31 & 7)) * 8));
                        y[db] = __builtin_amdgcn_mfma_f32_32x32x16_bf16(pa[ks].v, bv, y[db], 0, 0, 0);
                    }
                }
            }
            __syncthreads();   // publishes step-1 writes; all waves done reading buf[kt&1]
        }

        // ---- epilogue: normalize + store (register-only + global; no LDS) ----
        float linv = 1.0f / lrun;
        ushort_t* Yp = ybuf + (size_t)b * SEQ * DIM + hh * HD;
#pragma unroll
        for (int r = 0; r < 16; r++) {
            int qloc = (r & 3) + 8 * (r >> 2) + 4 * hf;
            float lr = __shfl(linv, qloc, 64);
            int q = qbase + qloc;
#pragma unroll
            for (int db = 0; db < 4; db++)
                Yp[(size_t)q * DIM + db * 32 + l31] = f2b(y[db][r] * lr);
        }
    }
}

extern "C" void kernel_launch(void* const* d_in, const int* in_sizes, int n_in,
                              void* d_out, int out_size, void* d_ws, size_t ws_size,
                              hipStream_t stream) {
    (void)in_sizes; (void)n_in; (void)out_size; (void)ws_size;
    const float* x     = (const float*)d_in[0];
    const float* wq    = (const float*)d_in[1];
    const float* wk    = (const float*)d_in[2];
    const float* wv    = (const float*)d_in[3];
    const float* wproj = (const float*)d_in[4];
    const float* qg    = (const float*)d_in[5];

    char* ws = (char*)d_ws;
    ushort_t* xb     = (ushort_t*)ws;                         // 16 MB
    ushort_t* wqkvb  = (ushort_t*)(ws + (16u << 20));         // 12 MB
    ushort_t* wprojb = (ushort_t*)(ws + (28u << 20));         // 8 MB
    ushort_t* qb     = (ushort_t*)(ws + (36u << 20));         // 16 MB
    ushort_t* kb     = (ushort_t*)(ws + (52u << 20));         // 4 MB
    ushort_t* vtb    = (ushort_t*)(ws + (56u << 20));         // 4 MB (V^T)
    ushort_t* yb     = (ushort_t*)(ws + (60u << 20));         // 16 MB

    cast_all<<<2048, 256, 0, stream>>>(x, wq, wk, wv, wproj, xb, wqkvb, wprojb);
    gemm_qkv<<<dim3(24, 32), 256, 0, stream>>>(xb, wqkvb, qg, qb, kb, vtb);
    attn<<<256, 512, 0, stream>>>(qb, kb, vtb, yb);
    gemm_bt<<<dim3(16, 32), 256, 0, stream>>>(yb, wprojb, (float*)d_out, 4096, 2048, 2048);
}

// Round 18
// 170.605 us; speedup vs baseline: 1.1597x; 1.1597x over previous
//
#include <hip/hip_runtime.h>
#include <hip/hip_bf16.h>
#include <stdint.h>

#define DIM 2048
#define NH 16
#define NKV 4
#define HD 128
#define BATCH 2
#define SEQ 2048

typedef unsigned short ushort_t;
typedef __attribute__((ext_vector_type(8))) short short8;
typedef __attribute__((ext_vector_type(4))) float f32x4;
typedef __attribute__((ext_vector_type(16))) float f32x16;

__device__ inline ushort_t f2b(float f) {
    union { float f; uint32_t u; } v; v.f = f;
    uint32_t r = (v.u + 0x7fffu + ((v.u >> 16) & 1u)) >> 16;
    return (ushort_t)r;
}

// native 2^x (v_exp_f32); libm exp2f goes through OCML precise path (r10: −13us on attn)
__device__ inline float fexp2(float x) {
#if __has_builtin(__builtin_amdgcn_exp2f)
    return __builtin_amdgcn_exp2f(x);
#else
    float r; asm("v_exp_f32 %0, %1" : "=v"(r) : "v"(x)); return r;
#endif
}

// packed f32x2 -> bf16x2 (T12 recipe; register-only asm, schedulable)
__device__ inline uint32_t pk2bf(float a, float b) {
    uint32_t r;
    asm("v_cvt_pk_bf16_f32 %0, %1, %2" : "=v"(r) : "v"(a), "v"(b));
    return r;
}

// merged cast: x->xb, wq/wk/wv->wqkvb (fused), wproj->wprojb  (one launch)
__global__ void cast_all(const float* __restrict__ x, const float* __restrict__ wq,
                         const float* __restrict__ wk, const float* __restrict__ wv,
                         const float* __restrict__ wp,
                         ushort_t* __restrict__ xb, ushort_t* __restrict__ wqkvb,
                         ushort_t* __restrict__ wprojb) {
    const int stride = gridDim.x * blockDim.x;
    for (int i = blockIdx.x * blockDim.x + threadIdx.x; i < 4718592; i += stride) {
        const float* s; ushort_t* d; int off;
        if (i < 2097152)      { s = x;  d = xb;               off = i; }
        else if (i < 3145728) { s = wq; d = wqkvb;            off = i - 2097152; }
        else if (i < 3407872) { s = wk; d = wqkvb + 4194304;  off = i - 3145728; }
        else if (i < 3670016) { s = wv; d = wqkvb + 5242880;  off = i - 3407872; }
        else                  { s = wp; d = wprojb;           off = i - 3670016; }
        float4 v = ((const float4*)s)[off];
        ushort4 o;
        o.x = f2b(v.x); o.y = f2b(v.y); o.z = f2b(v.z); o.w = f2b(v.w);
        ((ushort4*)d)[off] = o;
    }
}

__device__ inline void gload_lds16(const ushort_t* g, ushort_t* l) {
    __builtin_amdgcn_global_load_lds((const __attribute__((address_space(1))) void*)g,
                                     (__attribute__((address_space(3))) void*)l, 16, 0, 0);
}

// C[m][n] = sum_k A[m][k]*B[n][k], fp32 C (proj GEMM). BK=64 + source-XOR swizzle.
// T1 XCD-swizzled grid.
__launch_bounds__(256, 2)
__global__ void gemm_bt(const ushort_t* __restrict__ A, const ushort_t* __restrict__ Bm,
                        float* __restrict__ C, int M, int N, int K) {
    __shared__ ushort_t lA[128 * 64];
    __shared__ ushort_t lB[128 * 64];
    const int t = threadIdx.x;
    const int lane = t & 63;
    const int w = t >> 6;
    const int wr = w >> 1, wc = w & 1;
    const int g = lane >> 4, l16 = lane & 15;
    const int nwg = gridDim.x * gridDim.y;
    const int bid = blockIdx.y * gridDim.x + blockIdx.x;
    const int cpx = nwg >> 3;
    const int swz = (bid & 7) * cpx + (bid >> 3);
    const int nbx = gridDim.x;
    const int m0 = (swz / nbx) * 128, n0 = (swz % nbx) * 128;

    f32x4 acc[4][4];
#pragma unroll
    for (int i = 0; i < 4; i++)
#pragma unroll
        for (int j = 0; j < 4; j++) acc[i][j] = (f32x4){0, 0, 0, 0};

    const int row_s = t >> 3;              // 0..31 (+ i*32)
    const int cx = t & 7;                  // chunk 0..7; source chunk = cx ^ (row&7)
    const int xr = (lane & 7);             // read-side XOR term

    for (int kt = 0; kt < (K >> 6); ++kt) {
        const int k0 = kt * 64;
        __syncthreads();
#pragma unroll
        for (int i = 0; i < 4; i++) {
            const int ra = i * 32 + row_s;
            gload_lds16(A + (size_t)(m0 + ra) * K + k0 + ((cx ^ (row_s & 7)) * 8), lA + i * 2048 + t * 8);
            gload_lds16(Bm + (size_t)(n0 + ra) * K + k0 + ((cx ^ (row_s & 7)) * 8), lB + i * 2048 + t * 8);
        }
        __syncthreads();
#pragma unroll
        for (int kk = 0; kk < 2; kk++) {
            short8 af[4], bf[4];
#pragma unroll
            for (int i = 0; i < 4; i++) {
                af[i] = *(const short8*)(lA + (wr * 64 + i * 16 + l16) * 64 + (((kk * 4 + g) ^ xr) * 8));
                bf[i] = *(const short8*)(lB + (wc * 64 + i * 16 + l16) * 64 + (((kk * 4 + g) ^ xr) * 8));
            }
#pragma unroll
            for (int i = 0; i < 4; i++)
#pragma unroll
                for (int j = 0; j < 4; j++)
                    acc[i][j] = __builtin_amdgcn_mfma_f32_16x16x32_bf16(af[i], bf[j], acc[i][j], 0, 0, 0);
        }
    }
#pragma unroll
    for (int i = 0; i < 4; i++)
#pragma unroll
        for (int j = 0; j < 4; j++) {
            int rb = m0 + wr * 64 + i * 16 + g * 4;
            int cb = n0 + wc * 64 + j * 16 + l16;
#pragma unroll
            for (int r = 0; r < 4; r++)
                C[(size_t)(rb + r) * N + cb] = acc[i][j][r];
        }
}

// QKV GEMM (BK=64 + source swizzle) with fused RMSNorm+RoPE+gain epilogue (q/k) and
// transposed V write. n-tile == one head; cm[j] remap puts both RoPE partners in-lane.
__launch_bounds__(256, 2)
__global__ void gemm_qkv(const ushort_t* __restrict__ A, const ushort_t* __restrict__ Bm,
                         const float* __restrict__ qgain,
                         ushort_t* __restrict__ qb, ushort_t* __restrict__ kb,
                         ushort_t* __restrict__ vtb) {
    const int K = 2048;
    __shared__ ushort_t lA[128 * 64];
    __shared__ ushort_t lB[128 * 64];
    __shared__ float psum[2][128];
    const int t = threadIdx.x;
    const int lane = t & 63;
    const int w = t >> 6;
    const int wr = w >> 1, wc = w & 1;
    const int g = lane >> 4, l16 = lane & 15;
    const int nwg = gridDim.x * gridDim.y;
    const int bid = blockIdx.y * gridDim.x + blockIdx.x;
    const int cpx = nwg >> 3;
    const int swz = (bid & 7) * cpx + (bid >> 3);
    const int nt = swz % 24;                 // head tile: 0..15 q, 16..19 k, 20..23 v
    const int m0 = (swz / 24) * 128, n0 = nt * 128;

    int cm[4];
    cm[0] = wc * 32 + l16;
    cm[1] = wc * 32 + 16 + l16;
    cm[2] = cm[0] + 64;
    cm[3] = cm[1] + 64;

    f32x4 acc[4][4];
#pragma unroll
    for (int i = 0; i < 4; i++)
#pragma unroll
        for (int j = 0; j < 4; j++) acc[i][j] = (f32x4){0, 0, 0, 0};

    const int row_s = t >> 3;
    const int cx = t & 7;
    const int xr = (lane & 7);

    for (int kt = 0; kt < (K >> 6); ++kt) {
        const int k0 = kt * 64;
        __syncthreads();
#pragma unroll
        for (int i = 0; i < 4; i++) {
            const int ra = i * 32 + row_s;
            gload_lds16(A + (size_t)(m0 + ra) * K + k0 + ((cx ^ (row_s & 7)) * 8), lA + i * 2048 + t * 8);
            gload_lds16(Bm + (size_t)(n0 + ra) * K + k0 + ((cx ^ (row_s & 7)) * 8), lB + i * 2048 + t * 8);
        }
        __syncthreads();
#pragma unroll
        for (int kk = 0; kk < 2; kk++) {
            short8 af[4], bf[4];
#pragma unroll
            for (int i = 0; i < 4; i++) {
                af[i] = *(const short8*)(lA + (wr * 64 + i * 16 + l16) * 64 + (((kk * 4 + g) ^ xr) * 8));
                bf[i] = *(const short8*)(lB + cm[i] * 64 + (((kk * 4 + g) ^ xr) * 8));
            }
#pragma unroll
            for (int i = 0; i < 4; i++)
#pragma unroll
                for (int j = 0; j < 4; j++)
                    acc[i][j] = __builtin_amdgcn_mfma_f32_16x16x32_bf16(af[i], bf[j], acc[i][j], 0, 0, 0);
        }
    }

    const int b = m0 >> 11;          // token block lies within one batch (2048 % 128 == 0)
    const int s0 = m0 & 2047;

    if (nt < 20) {
        float ssq[4][4];
#pragma unroll
        for (int i = 0; i < 4; i++)
#pragma unroll
            for (int r = 0; r < 4; r++) {
                float v = 0.0f;
#pragma unroll
                for (int j = 0; j < 4; j++) v += acc[i][j][r] * acc[i][j][r];
#pragma unroll
                for (int m = 1; m < 16; m <<= 1) v += __shfl_xor(v, m, 64);
                ssq[i][r] = v;
            }
        if (l16 == 0) {
#pragma unroll
            for (int i = 0; i < 4; i++)
#pragma unroll
                for (int r = 0; r < 4; r++)
                    psum[wc][wr * 64 + i * 16 + g * 4 + r] = ssq[i][r];
        }
        __syncthreads();

        const float gsc = (nt < 16) ? qgain[nt] * (0.08838834764831845f * 1.4426950408889634f)
                                    : 1.0f;
        ushort_t* outp = (nt < 16) ? qb + (size_t)(b * NH + nt) * SEQ * HD
                                   : kb + (size_t)(b * NKV + (nt - 16)) * SEQ * HD;
        const float inv0 = exp2f(-(float)cm[0] * (13.287712379549449f / 64.0f));
        const float inv1 = exp2f(-(float)cm[1] * (13.287712379549449f / 64.0f));
#pragma unroll
        for (int i = 0; i < 4; i++)
#pragma unroll
            for (int r = 0; r < 4; r++) {
                const int sloc = wr * 64 + i * 16 + g * 4 + r;
                const float tot = psum[0][sloc] + psum[1][sloc];
                const float rg = rsqrtf(tot * (1.0f / 128.0f) + 1.1920929e-07f) * gsc;
                const float fs = (float)(s0 + sloc);
                ushort_t* orow = outp + (size_t)(s0 + sloc) * HD;
#pragma unroll
                for (int jp = 0; jp < 2; jp++) {
                    float x1 = acc[i][jp][r], x2 = acc[i][jp + 2][r];
                    float sn, c;
                    __sincosf(fs * (jp ? inv1 : inv0), &sn, &c);
                    orow[cm[jp]]      = f2b((x1 * c + x2 * sn) * rg);
                    orow[cm[jp] + 64] = f2b((x2 * c - x1 * sn) * rg);
                }
            }
    } else {
        ushort_t* vout = vtb + (size_t)((b * NKV + (nt - 20)) * HD) * SEQ;
#pragma unroll
        for (int i = 0; i < 4; i++)
#pragma unroll
            for (int j = 0; j < 4; j++) {
                ushort4 o;
                o.x = f2b(acc[i][j][0]); o.y = f2b(acc[i][j][1]);
                o.z = f2b(acc[i][j][2]); o.w = f2b(acc[i][j][3]);
                *(ushort4*)(vout + (size_t)cm[j] * SEQ + s0 + wr * 64 + i * 16 + g * 4) = o;
            }
    }
}

#define KVB 64

// 32x32 swapped-QK^T flash attention, 4 warps x 32 q-rows (r12/r16 configuration —
// empirical optimum of this design family; r13-r17 disproved: kv-split, 3-blocks/CU,
// and 8-wave merged blocks all regress. Two INDEPENDENT 4-wave blocks per CU provide
// the latency hiding: when one block sits at its barrier the other's waves run).
// T14 reg-staging + single-barrier double-buffered LDS: per iter
//   {ds_write tile k+1 -> buf[k+1&1]; global-load tile k+2 -> regs; compute buf[k&1]; barrier}.
// K LDS [64 kv][128 d]: chunk c at slot c ^ (row&15). V^T LDS [128 d][64 kv]: c ^ (row&7).
// Softmax exp2-domain (native v_exp); P-pack via v_cvt_pk_bf16_f32.
__launch_bounds__(256, 2)
__global__ void attn(const ushort_t* __restrict__ qbuf, const ushort_t* __restrict__ kbuf,
                     const ushort_t* __restrict__ vtbuf, ushort_t* __restrict__ ybuf) {
    __shared__ ushort_t Klds[2][KVB * HD];
    __shared__ ushort_t Vlds[2][HD * KVB];

    const int idx = blockIdx.x;
    const int pass = idx >> 8;
    const int rr0 = idx & 255;
    const int xcd = rr0 & 7;
    const int jj = rr0 >> 5;
    const int qt = pass ? jj : 15 - jj;    // slot-paired blocks sum to 19 tiles/CU-slot
    const int bh = xcd * 4 + ((rr0 >> 3) & 3);
    const int b = bh >> 4, hh = bh & 15;
    const int kvh = hh >> 2;
    const int t = threadIdx.x;
    const int w = t >> 6, lane = t & 63;
    const int l31 = lane & 31, hf = lane >> 5;
    const int q0 = qt * 128;
    const int qbase = q0 + w * 32;

    const ushort_t* Qp = qbuf + (size_t)(b * NH + hh) * SEQ * HD;
    const ushort_t* Kp = kbuf + (size_t)(b * NKV + kvh) * SEQ * HD;
    const ushort_t* Vtp = vtbuf + (size_t)(b * NKV + kvh) * HD * SEQ;

    short8 aq[8];
#pragma unroll
    for (int dc = 0; dc < 8; dc++)
        aq[dc] = *(const short8*)(Qp + (size_t)(qbase + l31) * HD + dc * 16 + hf * 8);

    f32x16 y[4];
#pragma unroll
    for (int db = 0; db < 4; db++)
#pragma unroll
        for (int r = 0; r < 16; r++) y[db][r] = 0.0f;
    float mrun = -1e30f, lrun = 0.0f;

    // staging: per-thread 64B of K (row t>>2, chunks (t&3)*4+i) and 64B of V^T
    // (row t>>1, chunks (t&1)*4+i). Linear global reads; swizzle applied on ds_write.
    const int k_row = t >> 2;
    const int k_c0 = (t & 3) * 4;
    const int v_row = t >> 1;
    const int v_c0 = (t & 1) * 4;

    short8 kreg[4], vreg[4];
    const int ntiles = q0 / 64 + 2;

    // prologue: tile 0 -> regs -> buf0; tile 1 -> regs; barrier
#pragma unroll
    for (int i = 0; i < 4; i++) {
        kreg[i] = *(const short8*)(Kp + (size_t)k_row * HD + (k_c0 + i) * 8);
        vreg[i] = *(const short8*)(Vtp + (size_t)v_row * SEQ + (v_c0 + i) * 8);
    }
    {
        ushort_t* kd = Klds[0] + k_row * HD;
        ushort_t* vd = Vlds[0] + v_row * KVB;
#pragma unroll
        for (int i = 0; i < 4; i++)
            *(short8*)(kd + (((k_c0 + i) ^ (k_row & 15)) * 8)) = kreg[i];
#pragma unroll
        for (int i = 0; i < 4; i++)
            *(short8*)(vd + (((v_c0 + i) ^ (v_row & 7)) * 8)) = vreg[i];
    }
    if (ntiles > 1) {
#pragma unroll
        for (int i = 0; i < 4; i++) {
            kreg[i] = *(const short8*)(Kp + (size_t)(KVB + k_row) * HD + (k_c0 + i) * 8);
            vreg[i] = *(const short8*)(Vtp + (size_t)v_row * SEQ + KVB + (v_c0 + i) * 8);
        }
    }
    __syncthreads();

    for (int kt = 0; kt < ntiles; ++kt) {
        const int kv0 = kt * KVB;
        // 1) publish tile kt+1 (from regs) into the other buffer
        if (kt + 1 < ntiles) {
            ushort_t* kd = Klds[(kt + 1) & 1] + k_row * HD;
            ushort_t* vd = Vlds[(kt + 1) & 1] + v_row * KVB;
#pragma unroll
            for (int i = 0; i < 4; i++)
                *(short8*)(kd + (((k_c0 + i) ^ (k_row & 15)) * 8)) = kreg[i];
#pragma unroll
            for (int i = 0; i < 4; i++)
                *(short8*)(vd + (((v_c0 + i) ^ (v_row & 7)) * 8)) = vreg[i];
        }
        // 2) issue global loads for tile kt+2 (latency hides under compute)
        if (kt + 2 < ntiles) {
            const int nkv0 = kv0 + 2 * KVB;
#pragma unroll
            for (int i = 0; i < 4; i++) {
                kreg[i] = *(const short8*)(Kp + (size_t)(nkv0 + k_row) * HD + (k_c0 + i) * 8);
                vreg[i] = *(const short8*)(Vtp + (size_t)v_row * SEQ + nkv0 + (v_c0 + i) * 8);
            }
        }

        // 3) compute tile kt from buf[kt&1]
        if (kv0 <= qbase + 31) {          // warp-uniform compute guard
            const ushort_t* Kl = Klds[kt & 1];
            const ushort_t* Vl = Vlds[kt & 1];

            f32x16 s0v, s1v;
#pragma unroll
            for (int r = 0; r < 16; r++) { s0v[r] = 0.0f; s1v[r] = 0.0f; }
#pragma unroll
            for (int dc = 0; dc < 8; dc++) {
                short8 ak0 = *(const short8*)(Kl + (size_t)(l31) * HD      + (((dc * 2 + hf) ^ (l31 & 15)) * 8));
                short8 ak1 = *(const short8*)(Kl + (size_t)(32 + l31) * HD + (((dc * 2 + hf) ^ (l31 & 15)) * 8));
                s0v = __builtin_amdgcn_mfma_f32_32x32x16_bf16(ak0, aq[dc], s0v, 0, 0, 0);
                s1v = __builtin_amdgcn_mfma_f32_32x32x16_bf16(ak1, aq[dc], s1v, 0, 0, 0);
            }

            // ---- causal mask ----
            const int qabs = qbase + l31;
            if (kv0 + 63 > qbase) {
#pragma unroll
                for (int r = 0; r < 16; r++) {
                    int kvr = kv0 + (r & 3) + 8 * (r >> 2) + 4 * hf;
                    if (kvr > qabs)      s0v[r] = -1e30f;
                    if (kvr + 32 > qabs) s1v[r] = -1e30f;
                }
            }

            // ---- softmax (per-lane q), online, exp2 domain, defer-max ----
            float mt = -1e30f;
#pragma unroll
            for (int r = 0; r < 16; r++) mt = fmaxf(mt, fmaxf(s0v[r], s1v[r]));
            mt = fmaxf(mt, __shfl_xor(mt, 32, 64));
            if (!__all(mt <= mrun + 8.0f)) {
                float mn = fmaxf(mrun, mt);
                float al = fexp2(mrun - mn);
                mrun = mn;
                lrun *= al;
#pragma unroll
                for (int r = 0; r < 16; r++) {
                    float alr = __shfl(al, (r & 3) + 8 * (r >> 2) + 4 * hf, 64);
#pragma unroll
                    for (int db = 0; db < 4; db++) y[db][r] *= alr;
                }
            }
            float sum = 0.0f;
#pragma unroll
            for (int r = 0; r < 16; r++) {
                float p0 = fexp2(s0v[r] - mrun);
                float p1 = fexp2(s1v[r] - mrun);
                s0v[r] = p0; s1v[r] = p1;
                sum += p0 + p1;
            }
            sum += __shfl_xor(sum, 32, 64);
            lrun += sum;

            // ---- P -> A-fragments: cvt_pk pack + lane^32 exchange ----
            union PW { short8 v; uint32_t wd[4]; } pa[4];
#pragma unroll
            for (int blk = 0; blk < 2; blk++) {
#pragma unroll
                for (int ks2 = 0; ks2 < 2; ks2++) {
#pragma unroll
                    for (int t2 = 0; t2 < 2; t2++) {
                        float a0 = blk ? s1v[8 * ks2 + 2 * t2]         : s0v[8 * ks2 + 2 * t2];
                        float a1 = blk ? s1v[8 * ks2 + 2 * t2 + 1]     : s0v[8 * ks2 + 2 * t2 + 1];
                        float b0 = blk ? s1v[8 * ks2 + 4 + 2 * t2]     : s0v[8 * ks2 + 4 + 2 * t2];
                        float b1 = blk ? s1v[8 * ks2 + 4 + 2 * t2 + 1] : s0v[8 * ks2 + 4 + 2 * t2 + 1];
                        uint32_t pw = pk2bf(a0, a1);   // low pair
                        uint32_t qw = pk2bf(b0, b1);   // high pair
                        uint32_t send = hf ? pw : qw;
                        uint32_t recv = (uint32_t)__shfl_xor((int)send, 32, 64);
                        pa[blk * 2 + ks2].wd[t2]     = hf ? recv : pw;
                        pa[blk * 2 + ks2].wd[t2 + 2] = hf ? qw : recv;
                    }
                }
            }

            // ---- PV: y[db] += sum_ks pa[ks] x V^T-frag ----
#pragma unroll
            for (int ks = 0; ks < 4; ks++) {
#pragma unroll
                for (int db = 0; db < 4; db++) {
                    short8 bv = *(const short8*)(Vl + (size_t)(db * 32 + l31) * KVB
                                                 + (((ks * 2 + hf) ^ (l31 & 7)) * 8));
                    y[db] = __builtin_amdgcn_mfma_f32_32x32x16_bf16(pa[ks].v, bv, y[db], 0, 0, 0);
                }
            }
        }
        __syncthreads();   // publishes step-1 writes; all warps done reading buf[kt&1]
    }

    // ---- epilogue: normalize + store ----
    float linv = 1.0f / lrun;
    ushort_t* Yp = ybuf + (size_t)b * SEQ * DIM + hh * HD;
#pragma unroll
    for (int r = 0; r < 16; r++) {
        int qloc = (r & 3) + 8 * (r >> 2) + 4 * hf;
        float lr = __shfl(linv, qloc, 64);
        int q = qbase + qloc;
#pragma unroll
        for (int db = 0; db < 4; db++)
            Yp[(size_t)q * DIM + db * 32 + l31] = f2b(y[db][r] * lr);
    }
}

extern "C" void kernel_launch(void* const* d_in, const int* in_sizes, int n_in,
                              void* d_out, int out_size, void* d_ws, size_t ws_size,
                              hipStream_t stream) {
    (void)in_sizes; (void)n_in; (void)out_size; (void)ws_size;
    const float* x     = (const float*)d_in[0];
    const float* wq    = (const float*)d_in[1];
    const float* wk    = (const float*)d_in[2];
    const float* wv    = (const float*)d_in[3];
    const float* wproj = (const float*)d_in[4];
    const float* qg    = (const float*)d_in[5];

    char* ws = (char*)d_ws;
    ushort_t* xb     = (ushort_t*)ws;                         // 16 MB
    ushort_t* wqkvb  = (ushort_t*)(ws + (16u << 20));         // 12 MB
    ushort_t* wprojb = (ushort_t*)(ws + (28u << 20));         // 8 MB
    ushort_t* qb     = (ushort_t*)(ws + (36u << 20));         // 16 MB
    ushort_t* kb     = (ushort_t*)(ws + (52u << 20));         // 4 MB
    ushort_t* vtb    = (ushort_t*)(ws + (56u << 20));         // 4 MB (V^T)
    ushort_t* yb     = (ushort_t*)(ws + (60u << 20));         // 16 MB

    cast_all<<<2048, 256, 0, stream>>>(x, wq, wk, wv, wproj, xb, wqkvb, wprojb);
    gemm_qkv<<<dim3(24, 32), 256, 0, stream>>>(xb, wqkvb, qg, qb, kb, vtb);
    attn<<<512, 256, 0, stream>>>(qb, kb, vtb, yb);
    gemm_bt<<<dim3(16, 32), 256, 0, stream>>>(yb, wprojb, (float*)d_out, 4096, 2048, 2048);
}